// Round 9
// baseline (6103.254 us; speedup 1.0000x reference)
//
#include <hip/hip_runtime.h>

#define Bsz 2048
#define Ssz 96
#define Fsz 32
#define Hsz 256
#define Osz 6
#define LAsz 32
#define RT 8                  // batch rows per block; grid = 256 = 1 block/CU
#define NSTEP (Ssz + LAsz)
#define NTHR 512              // 8 waves
#define NKT 9                 // K-tiles of 32 over virtual K = 32(x) + 256(h) = 288
#define NGT 64                // gate tiles of 16 (4*256/16)
#define GLW 1044              // f32 row stride of gate_lds
// fp16 2-way split scaling (all exact powers of 2):
#define SCL   1024.0f
#define SRES  2048.0f
#define INV_SR   4.8828125e-4f          // 2^-11
#define INV_SR2  2.384185791015625e-7f  // 2^-22
#define INV_SWH  9.5367431640625e-07    // 2^-20 (applied in f64 combine)

typedef __attribute__((ext_vector_type(8))) short    short8;
typedef __attribute__((ext_vector_type(8))) _Float16 half8;
typedef __attribute__((ext_vector_type(4))) float    f32x4;
typedef __attribute__((ext_vector_type(4))) unsigned int uint4v;

__device__ __forceinline__ half8 as_h8(uint4v v) {
    union { uint4v u; half8 h; } c; c.u = v; return c.h;
}
__device__ __forceinline__ half8 as_h8s(short8 v) {
    union { short8 s; half8 h; } c; c.s = v; return c.h;
}
#define MFMAF16(A, B, C) \
    __builtin_amdgcn_mfma_f32_16x16x32_f16(as_h8(A), as_h8s(B), (C), 0, 0, 0)

__device__ __forceinline__ unsigned short f16_rne(float f) {
    union { _Float16 h; unsigned short u; } c; c.h = (_Float16)f; return c.u;
}
__device__ __forceinline__ float f16_to_f(unsigned short u) {
    union { _Float16 h; unsigned short u; } c; c.u = u; return (float)c.h;
}

// lgkm-only barrier: orders LDS writes/reads across waves WITHOUT draining vmcnt,
// so global (weight) loads stay in flight across phases. All in-loop cross-wave
// deps are through LDS, so this is semantically sufficient.
__device__ __forceinline__ void lgkm_barrier() {
    asm volatile("s_waitcnt lgkmcnt(0)" ::: "memory");
    __builtin_amdgcn_s_barrier();
    asm volatile("" ::: "memory");
}

// fragment LDS index: [kt][half][slot][elem] ushorts; slot for (r16,kg) = (kg<<4)|r16
#define FIDX(kt, half, slot, elem) (((((kt) * 2 + (half)) * 64) + (slot)) * 8 + (elem))

// ---------- accurate f64 exp (|rel err| ~1e-14) ----------
__device__ __forceinline__ double exp_d(double x) {
    x = fmin(fmax(x, -700.0), 700.0);
    const double LOG2E = 1.4426950408889634074;
    const double LN2HI = 6.93147180369123816490e-01;
    const double LN2LO = 1.90821492927058770002e-10;
    double n = __builtin_rint(x * LOG2E);
    double r = fma(-n, LN2HI, x);
    r = fma(-n, LN2LO, r);
    double p = 2.5052108385441718775e-08;
    p = fma(p, r, 2.7557319223985890653e-07);
    p = fma(p, r, 2.7557319223985892511e-06);
    p = fma(p, r, 2.4801587301587301566e-05);
    p = fma(p, r, 1.9841269841269841253e-04);
    p = fma(p, r, 1.3888888888888889419e-03);
    p = fma(p, r, 8.3333333333333332177e-03);
    p = fma(p, r, 4.1666666666666664354e-02);
    p = fma(p, r, 1.6666666666666665741e-01);
    p = fma(p, r, 5.0e-01);
    p = fma(p, r, 1.0);
    p = fma(p, r, 1.0);
    long long bits = (long long)(1023 + (int)n) << 52;
    return p * __longlong_as_double(bits);
}
__device__ __forceinline__ double recip_d(double y) {
    double r = (double)(1.0f / (float)y);
    r = fma(fma(-y, r, 1.0), r, r);
    r = fma(fma(-y, r, 1.0), r, r);
    r = fma(fma(-y, r, 1.0), r, r);
    return r;
}
__device__ __forceinline__ double sigmoid_d(double x) { return recip_d(1.0 + exp_d(-x)); }
__device__ __forceinline__ double tanh_d(double x) {
    double ax = fabs(x);
    double t = exp_d(-2.0 * ax);
    double r = (1.0 - t) * recip_d(1.0 + t);
    return x >= 0.0 ? r : -r;
}

// ---------- pre-pass: pack W into scaled fp16 2-way-split MFMA A-fragments ----------
__global__ void pack_w(const float* __restrict__ W_ih,
                       const float* __restrict__ W_hh,
                       unsigned short* __restrict__ wfrag)
{
    int idx = blockIdx.x * 256 + threadIdx.x;
    if (idx >= NGT * NKT * 64) return;
    int L  = idx & 63;
    int tk = idx >> 6;
    int kt = tk % NKT, gt = tk / NKT;
    int gate = gt * 16 + (L & 15);
    int kg   = L >> 4;
    unsigned short* p = wfrag + (size_t)idx * 16;
    #pragma unroll
    for (int i = 0; i < 8; ++i) {
        int vk = kt * 32 + kg * 8 + i;
        float wv = (vk < Fsz) ? W_ih[(size_t)gate * Fsz + vk]
                              : W_hh[(size_t)gate * Hsz + (vk - Fsz)];
        float ws = wv * SCL;
        unsigned short w0 = f16_rne(ws);
        float r1 = ws - f16_to_f(w0);            // exact (Sterbenz)
        p[i]     = w0;
        p[8 + i] = f16_rne(r1 * SRES);
    }
}

// load one gate-tile's 18 records into a named register buffer (static kt unroll)
#define LOADGT(D0, D1, gtid)                                                  \
    do {                                                                      \
        _Pragma("unroll")                                                     \
        for (int kt = 0; kt < NKT; ++kt) {                                    \
            const uint4v* rp =                                                \
                (const uint4v*)(wb8 + ((size_t)((gtid) * NKT + kt)) * 2048);  \
            D0[kt] = rp[0];                                                   \
            D1[kt] = rp[1];                                                   \
        }                                                                     \
    } while (0)

// consume one gate-tile buffer: 4 independent MFMA chains, then epilogue store
#define GEMMGT(S0, S1, gtid)                                                  \
    do {                                                                      \
        f32x4 c0  = {0.f, 0.f, 0.f, 0.f};                                     \
        f32x4 c1a = {0.f, 0.f, 0.f, 0.f};                                     \
        f32x4 c1b = {0.f, 0.f, 0.f, 0.f};                                     \
        f32x4 c2  = {0.f, 0.f, 0.f, 0.f};                                     \
        _Pragma("unroll")                                                     \
        for (int kt = 0; kt < NKT; ++kt) {                                    \
            short8 blk = *(const short8*)&xfrag[FIDX(kt, 1, l, 0)];           \
            c0  = MFMAF16(S0[kt], bh[kt], c0);                                \
            c1a = MFMAF16(S0[kt], blk, c1a);                                  \
            c1b = MFMAF16(S1[kt], bh[kt], c1b);                               \
            c2  = MFMAF16(S1[kt], blk, c2);                                   \
        }                                                                     \
        if (r16 < RT) {                                                       \
            f32x4 s;                                                          \
            s.x = fmaf(c2.x, INV_SR2, fmaf(c1a.x + c1b.x, INV_SR, c0.x));     \
            s.y = fmaf(c2.y, INV_SR2, fmaf(c1a.y + c1b.y, INV_SR, c0.y));     \
            s.z = fmaf(c2.z, INV_SR2, fmaf(c1a.z + c1b.z, INV_SR, c0.z));     \
            s.w = fmaf(c2.w, INV_SR2, fmaf(c1a.w + c1b.w, INV_SR, c0.w));     \
            *(f32x4*)&gate_lds[r16 * GLW + ((w * 8 + (gtid)) << 4) + (kg << 2)] = s; \
        }                                                                     \
    } while (0)

__global__ __launch_bounds__(NTHR, 2) void lstm_persist(
    const float* __restrict__ x,
    const unsigned short* __restrict__ wfrag,
    const float* __restrict__ b_ih, const float* __restrict__ b_hh,
    const float* __restrict__ W_fc, const float* __restrict__ b_fc,
    float* __restrict__ out)
{
    __shared__ __align__(16) unsigned short xfrag[NKT * 2 * 64 * 8];  // 18 KB
    __shared__ __align__(16) float gate_lds[RT * GLW];                // 33.4 KB
    __shared__ __align__(16) float h_f32[RT * Hsz];                   // 8 KB
    __shared__ float  wfc_lds[Osz * Hsz];                             // 6 KB

    const int tid   = threadIdx.x;
    const int row0  = blockIdx.x * RT;
    const int w     = tid >> 6;                    // wave id (owns batch row w)
    const int l     = tid & 63;
    const int j     = (w << 5) + (l & 31);         // activation channel owned
    const int q     = l >> 5;
    const int rbase = q * 4;                       // activation rows owned
    const int r16   = l & 15;                      // MFMA: batch row (N)
    const int kg    = l >> 4;                      // MFMA: k-group

    for (int i = tid; i < NKT * 2 * 64 * 8; i += NTHR) xfrag[i] = 0;
    for (int i = tid; i < Osz * Hsz; i += NTHR) wfc_lds[i] = W_fc[i];

    const double bias0 = (double)b_ih[0 * Hsz + j] + (double)b_hh[0 * Hsz + j];
    const double bias1 = (double)b_ih[1 * Hsz + j] + (double)b_hh[1 * Hsz + j];
    const double bias2 = (double)b_ih[2 * Hsz + j] + (double)b_hh[2 * Hsz + j];
    const double bias3 = (double)b_ih[3 * Hsz + j] + (double)b_hh[3 * Hsz + j];

    double c_reg[4];
    #pragma unroll
    for (int r = 0; r < 4; ++r) c_reg[r] = 0.0;

    // wave w owns gate-tiles w*8 .. w*8+7; per-lane record byte base
    const char* wb8 = (const char*)wfrag + ((size_t)(w * 8) * NKT * 64 + l) * 32;
    const int ktw = w + 1;                         // h-write K-tile for this wave

    float ofeed = 0.0f;                            // lane f<6: o feedback value

    // prologue: preload gt0 / gt1 into the two rotating buffers
    uint4v A0[NKT], A1[NKT], C0[NKT], C1[NKT];
    LOADGT(A0, A1, 0);
    LOADGT(C0, C1, 1);

    __syncthreads();

    for (int t = 0; t < NSTEP; ++t) {
        // ---- stage row w's x (or o feedback), scaled fp16 2-split, kt=0 tile ----
        if (l < 32) {
            int f = l;
            int ts = (t < Ssz) ? t : (t - Ssz);
            float v;
            if (t >= Ssz && f < Osz) v = ofeed;
            else v = x[((size_t)(row0 + w) * Ssz + ts) * Fsz + f];
            float vs = v * SCL;
            unsigned short u0 = f16_rne(vs);
            float r1 = vs - f16_to_f(u0);
            int slot = ((f >> 3) << 4) | w;
            xfrag[FIDX(0, 0, slot, f & 7)] = u0;
            xfrag[FIDX(0, 1, slot, f & 7)] = f16_rne(r1 * SRES);
        }
        lgkm_barrier();                              // A: fragments complete

        // ---- bh fragments to registers once (9 x ds_read_b128) ----
        short8 bh[NKT];
        #pragma unroll
        for (int kt = 0; kt < NKT; ++kt)
            bh[kt] = *(const short8*)&xfrag[FIDX(kt, 0, l, 0)];

        // ---- pipelined gate GEMM: consume gt g, issue gt g+2; the last two
        //      LOADs target NEXT STEP's gt0/gt1 and fly through the activation
        //      phase (lgkm-only barriers never drain vmcnt) ----
        GEMMGT(A0, A1, 0);  LOADGT(A0, A1, 2);
        GEMMGT(C0, C1, 1);  LOADGT(C0, C1, 3);
        GEMMGT(A0, A1, 2);  LOADGT(A0, A1, 4);
        GEMMGT(C0, C1, 3);  LOADGT(C0, C1, 5);
        GEMMGT(A0, A1, 4);  LOADGT(A0, A1, 6);
        GEMMGT(C0, C1, 5);  LOADGT(C0, C1, 7);
        GEMMGT(A0, A1, 6);  LOADGT(A0, A1, 0);     // next step gt0
        GEMMGT(C0, C1, 7);  LOADGT(C0, C1, 1);     // next step gt1
        lgkm_barrier();                              // B: gates published

        // ---- activations: EXACT f64 path (unchanged numerics) ----
        float gv0[4], gv1[4], gv2[4], gv3[4];
        #pragma unroll
        for (int rr = 0; rr < 4; ++rr) {
            int rowb = (rbase + rr) * GLW;
            gv0[rr] = gate_lds[rowb + 0 * Hsz + j];
            gv1[rr] = gate_lds[rowb + 1 * Hsz + j];
            gv2[rr] = gate_lds[rowb + 2 * Hsz + j];
            gv3[rr] = gate_lds[rowb + 3 * Hsz + j];
        }
        #pragma unroll
        for (int rr = 0; rr < 4; ++rr) {
            double t0 = bias0 + (double)gv0[rr] * INV_SWH;
            double t1 = bias1 + (double)gv1[rr] * INV_SWH;
            double t2 = bias2 + (double)gv2[rr] * INV_SWH;
            double t3 = bias3 + (double)gv3[rr] * INV_SWH;
            double si = sigmoid_d(t0);
            double sf = sigmoid_d(t1);
            double tg = tanh_d(t2);
            double so = sigmoid_d(t3);
            double cn = fma(sf, c_reg[rr], si * tg);
            c_reg[rr] = cn;
            float hf = (float)(so * tanh_d(cn));
            int row = rbase + rr;
            int i32 = j & 31;
            int slot = ((i32 >> 3) << 4) | row;
            float hs = hf * SCL;
            unsigned short u0 = f16_rne(hs);
            float r1 = hs - f16_to_f(u0);
            xfrag[FIDX(ktw, 0, slot, i32 & 7)] = u0;
            xfrag[FIDX(ktw, 1, slot, i32 & 7)] = f16_rne(r1 * SRES);
            if (t >= Ssz - 1) h_f32[row * Hsz + j] = hf;   // exact h for STE readout
        }

        // ---- readout: wave w owns row w (STE f32, dot f64 — unchanged) ----
        if (t >= Ssz - 1) {
            lgkm_barrier();                          // C: h complete
            double a0 = 0.0, a1 = 0.0, a2 = 0.0, a3 = 0.0, a4 = 0.0, a5 = 0.0;
            #pragma unroll
            for (int m = 0; m < 4; ++m) {
                int k = l + 64 * m;
                float hv = h_f32[w * Hsz + k];
                bool b = hv > 0.0f;
                a0 += b ? (double)wfc_lds[0 * Hsz + k] : 0.0;
                a1 += b ? (double)wfc_lds[1 * Hsz + k] : 0.0;
                a2 += b ? (double)wfc_lds[2 * Hsz + k] : 0.0;
                a3 += b ? (double)wfc_lds[3 * Hsz + k] : 0.0;
                a4 += b ? (double)wfc_lds[4 * Hsz + k] : 0.0;
                a5 += b ? (double)wfc_lds[5 * Hsz + k] : 0.0;
            }
            #pragma unroll
            for (int off = 32; off >= 1; off >>= 1) {
                a0 += __shfl_down(a0, off, 64);
                a1 += __shfl_down(a1, off, 64);
                a2 += __shfl_down(a2, off, 64);
                a3 += __shfl_down(a3, off, 64);
                a4 += __shfl_down(a4, off, 64);
                a5 += __shfl_down(a5, off, 64);
            }
            double o0 = (double)b_fc[0] + a0;
            double o1 = (double)b_fc[1] + a1;
            double o2 = (double)b_fc[2] + a2;
            double o3 = (double)b_fc[3] + a3;
            double o4 = (double)b_fc[4] + a4;
            double o5 = (double)b_fc[5] + a5;
            if (l == 0) {
                size_t base = ((size_t)(row0 + w) * (LAsz + 1) + (t - (Ssz - 1))) * Osz;
                out[base + 0] = (float)o0;
                out[base + 1] = (float)o1;
                out[base + 2] = (float)o2;
                out[base + 3] = (float)o3;
                out[base + 4] = (float)o4;
                out[base + 5] = (float)o5;
            }
            // intra-wave o feedback: broadcast lane 0's values, lane f keeps o_f
            double b0 = __shfl(o0, 0, 64);
            double b1 = __shfl(o1, 0, 64);
            double b2 = __shfl(o2, 0, 64);
            double b3 = __shfl(o3, 0, 64);
            double b4 = __shfl(o4, 0, 64);
            double b5 = __shfl(o5, 0, 64);
            ofeed = (float)((l == 0) ? b0 : (l == 1) ? b1 : (l == 2) ? b2 :
                            (l == 3) ? b3 : (l == 4) ? b4 : (l == 5) ? b5 : 0.0);
            // no barrier D needed: feedback is now register-resident per wave
        }
        // next iteration's barrier A orders this step's h/x LDS writes vs reads
    }
}

extern "C" void kernel_launch(void* const* d_in, const int* in_sizes, int n_in,
                              void* d_out, int out_size, void* d_ws, size_t ws_size,
                              hipStream_t stream)
{
    const float* x    = (const float*)d_in[0];
    const float* W_ih = (const float*)d_in[1];
    const float* W_hh = (const float*)d_in[2];
    const float* b_ih = (const float*)d_in[3];
    const float* b_hh = (const float*)d_in[4];
    const float* W_fc = (const float*)d_in[5];
    const float* b_fc = (const float*)d_in[6];
    float* out = (float*)d_out;

    unsigned short* wfrag = (unsigned short*)d_ws;   // 64*9*64*32 B = 1.125 MB

    pack_w<<<dim3((NGT * NKT * 64 + 255) / 256), dim3(256), 0, stream>>>(
        W_ih, W_hh, wfrag);

    lstm_persist<<<dim3(Bsz / RT), dim3(NTHR), 0, stream>>>(
        x, wfrag, b_ih, b_hh, W_fc, b_fc, out);
}

// Round 10
// 6101.606 us; speedup vs baseline: 1.0003x; 1.0003x over previous
//
#include <hip/hip_runtime.h>

#define Bsz 2048
#define Ssz 96
#define Fsz 32
#define Hsz 256
#define Osz 6
#define LAsz 32
#define RT 8                  // batch rows per block; grid = 256 = 1 block/CU
#define NSTEP (Ssz + LAsz)
#define NTHR 512              // 8 waves
#define NKT 9                 // K-tiles of 32 over virtual K = 32(x) + 256(h) = 288
#define NGT 64                // gate tiles of 16 (4*256/16)
#define GLW 1044              // f32 row stride of gate_lds
// fp16 2-way split scaling (all exact powers of 2):
#define SCL   1024.0f
#define SRES  2048.0f
#define INV_SR   4.8828125e-4f          // 2^-11
#define INV_SR2  2.384185791015625e-7f  // 2^-22
#define INV_SWH  9.5367431640625e-07    // 2^-20 (applied in f64 combine)

typedef __attribute__((ext_vector_type(8))) short    short8;
typedef __attribute__((ext_vector_type(8))) _Float16 half8;
typedef __attribute__((ext_vector_type(4))) float    f32x4;
typedef __attribute__((ext_vector_type(4))) unsigned int uint4v;

__device__ __forceinline__ half8 as_h8(uint4v v) {
    union { uint4v u; half8 h; } c; c.u = v; return c.h;
}
__device__ __forceinline__ half8 as_h8s(short8 v) {
    union { short8 s; half8 h; } c; c.s = v; return c.h;
}
#define MFMAF16(A, B, C) \
    __builtin_amdgcn_mfma_f32_16x16x32_f16(as_h8(A), as_h8s(B), (C), 0, 0, 0)

__device__ __forceinline__ unsigned short f16_rne(float f) {
    union { _Float16 h; unsigned short u; } c; c.h = (_Float16)f; return c.u;
}
__device__ __forceinline__ float f16_to_f(unsigned short u) {
    union { _Float16 h; unsigned short u; } c; c.u = u; return (float)c.h;
}

// lgkm-only barrier: orders LDS writes/reads across waves WITHOUT draining vmcnt,
// so global (weight) loads stay in flight across phases.
__device__ __forceinline__ void lgkm_barrier() {
    asm volatile("s_waitcnt lgkmcnt(0)" ::: "memory");
    __builtin_amdgcn_s_barrier();
    asm volatile("" ::: "memory");
}

// fragment LDS index: [kt][half][slot][elem] ushorts; slot for (r16,kg) = (kg<<4)|r16
#define FIDX(kt, half, slot, elem) (((((kt) * 2 + (half)) * 64) + (slot)) * 8 + (elem))

// ---------- accurate f64 exp (|rel err| ~1e-14) ----------
__device__ __forceinline__ double exp_d(double x) {
    x = fmin(fmax(x, -700.0), 700.0);
    const double LOG2E = 1.4426950408889634074;
    const double LN2HI = 6.93147180369123816490e-01;
    const double LN2LO = 1.90821492927058770002e-10;
    double n = __builtin_rint(x * LOG2E);
    double r = fma(-n, LN2HI, x);
    r = fma(-n, LN2LO, r);
    double p = 2.5052108385441718775e-08;
    p = fma(p, r, 2.7557319223985890653e-07);
    p = fma(p, r, 2.7557319223985892511e-06);
    p = fma(p, r, 2.4801587301587301566e-05);
    p = fma(p, r, 1.9841269841269841253e-04);
    p = fma(p, r, 1.3888888888888889419e-03);
    p = fma(p, r, 8.3333333333333332177e-03);
    p = fma(p, r, 4.1666666666666664354e-02);
    p = fma(p, r, 1.6666666666666665741e-01);
    p = fma(p, r, 5.0e-01);
    p = fma(p, r, 1.0);
    p = fma(p, r, 1.0);
    long long bits = (long long)(1023 + (int)n) << 52;
    return p * __longlong_as_double(bits);
}
__device__ __forceinline__ double recip_d(double y) {
    double r = (double)(1.0f / (float)y);
    r = fma(fma(-y, r, 1.0), r, r);
    r = fma(fma(-y, r, 1.0), r, r);
    r = fma(fma(-y, r, 1.0), r, r);
    return r;
}
__device__ __forceinline__ double sigmoid_d(double x) { return recip_d(1.0 + exp_d(-x)); }
__device__ __forceinline__ double tanh_d(double x) {
    double ax = fabs(x);
    double t = exp_d(-2.0 * ax);
    double r = (1.0 - t) * recip_d(1.0 + t);
    return x >= 0.0 ? r : -r;
}

// ---------- pre-pass: pack W into scaled fp16 2-way-split MFMA A-fragments ----------
__global__ void pack_w(const float* __restrict__ W_ih,
                       const float* __restrict__ W_hh,
                       unsigned short* __restrict__ wfrag)
{
    int idx = blockIdx.x * 256 + threadIdx.x;
    if (idx >= NGT * NKT * 64) return;
    int L  = idx & 63;
    int tk = idx >> 6;
    int kt = tk % NKT, gt = tk / NKT;
    int gate = gt * 16 + (L & 15);
    int kg   = L >> 4;
    unsigned short* p = wfrag + (size_t)idx * 16;
    #pragma unroll
    for (int i = 0; i < 8; ++i) {
        int vk = kt * 32 + kg * 8 + i;
        float wv = (vk < Fsz) ? W_ih[(size_t)gate * Fsz + vk]
                              : W_hh[(size_t)gate * Hsz + (vk - Fsz)];
        float ws = wv * SCL;
        unsigned short w0 = f16_rne(ws);
        float r1 = ws - f16_to_f(w0);            // exact (Sterbenz)
        p[i]     = w0;
        p[8 + i] = f16_rne(r1 * SRES);
    }
}

// load one gate-tile's 18 records into a named register buffer (static kt unroll)
#define LOADGT(D0, D1, gtid)                                                  \
    do {                                                                      \
        _Pragma("unroll")                                                     \
        for (int kt = 0; kt < NKT; ++kt) {                                    \
            const uint4v* rp =                                                \
                (const uint4v*)(wb8 + ((size_t)((gtid) * NKT + kt)) * 2048);  \
            D0[kt] = rp[0];                                                   \
            D1[kt] = rp[1];                                                   \
        }                                                                     \
    } while (0)

// consume one gate-tile buffer: 4 independent MFMA chains, then epilogue store
#define GEMMGT(S0, S1, gtid)                                                  \
    do {                                                                      \
        f32x4 c0  = {0.f, 0.f, 0.f, 0.f};                                     \
        f32x4 c1a = {0.f, 0.f, 0.f, 0.f};                                     \
        f32x4 c1b = {0.f, 0.f, 0.f, 0.f};                                     \
        f32x4 c2  = {0.f, 0.f, 0.f, 0.f};                                     \
        _Pragma("unroll")                                                     \
        for (int kt = 0; kt < NKT; ++kt) {                                    \
            short8 blk = *(const short8*)&xfrag[FIDX(kt, 1, l, 0)];           \
            c0  = MFMAF16(S0[kt], bh[kt], c0);                                \
            c1a = MFMAF16(S0[kt], blk, c1a);                                  \
            c1b = MFMAF16(S1[kt], bh[kt], c1b);                               \
            c2  = MFMAF16(S1[kt], blk, c2);                                   \
        }                                                                     \
        if (r16 < RT) {                                                       \
            f32x4 s;                                                          \
            s.x = fmaf(c2.x, INV_SR2, fmaf(c1a.x + c1b.x, INV_SR, c0.x));     \
            s.y = fmaf(c2.y, INV_SR2, fmaf(c1a.y + c1b.y, INV_SR, c0.y));     \
            s.z = fmaf(c2.z, INV_SR2, fmaf(c1a.z + c1b.z, INV_SR, c0.z));     \
            s.w = fmaf(c2.w, INV_SR2, fmaf(c1a.w + c1b.w, INV_SR, c0.w));     \
            *(f32x4*)&gate_lds[r16 * GLW + ((w * 8 + (gtid)) << 4) + (kg << 2)] = s; \
        }                                                                     \
    } while (0)

__global__ __launch_bounds__(NTHR, 1) void lstm_persist(
    const float* __restrict__ x,
    const unsigned short* __restrict__ wfrag,
    const float* __restrict__ b_ih, const float* __restrict__ b_hh,
    const float* __restrict__ W_fc, const float* __restrict__ b_fc,
    float* __restrict__ out)
{
    __shared__ __align__(16) unsigned short xfrag[NKT * 2 * 64 * 8];  // 18 KB
    __shared__ __align__(16) float gate_lds[RT * GLW];                // 33.4 KB
    __shared__ __align__(16) float h_f32[RT * Hsz];                   // 8 KB
    __shared__ float  wfc_lds[Osz * Hsz];                             // 6 KB

    const int tid   = threadIdx.x;
    const int row0  = blockIdx.x * RT;
    const int w     = tid >> 6;                    // wave id (owns batch row w)
    const int l     = tid & 63;
    const int j     = (w << 5) + (l & 31);         // activation channel owned
    const int q     = l >> 5;
    const int rbase = q * 4;                       // activation rows owned
    const int r16   = l & 15;                      // MFMA: batch row (N)
    const int kg    = l >> 4;                      // MFMA: k-group

    for (int i = tid; i < NKT * 2 * 64 * 8; i += NTHR) xfrag[i] = 0;
    for (int i = tid; i < Osz * Hsz; i += NTHR) wfc_lds[i] = W_fc[i];

    const double bias0 = (double)b_ih[0 * Hsz + j] + (double)b_hh[0 * Hsz + j];
    const double bias1 = (double)b_ih[1 * Hsz + j] + (double)b_hh[1 * Hsz + j];
    const double bias2 = (double)b_ih[2 * Hsz + j] + (double)b_hh[2 * Hsz + j];
    const double bias3 = (double)b_ih[3 * Hsz + j] + (double)b_hh[3 * Hsz + j];

    double c_reg[4];
    #pragma unroll
    for (int r = 0; r < 4; ++r) c_reg[r] = 0.0;

    // wave w owns gate-tiles w*8 .. w*8+7; per-lane record byte base
    const char* wb8 = (const char*)wfrag + ((size_t)(w * 8) * NKT * 64 + l) * 32;
    const int ktw = w + 1;                         // h-write K-tile for this wave

    float ofeed = 0.0f;                            // lane f<6: o feedback value

    // prologue: preload gt0 / gt1 into the two rotating buffers
    uint4v A0[NKT], A1[NKT], C0[NKT], C1[NKT];
    LOADGT(A0, A1, 0);
    LOADGT(C0, C1, 1);

    __syncthreads();

    for (int t = 0; t < NSTEP; ++t) {
        // ---- stage row w's x (or o feedback), scaled fp16 2-split, kt=0 tile ----
        if (l < 32) {
            int f = l;
            int ts = (t < Ssz) ? t : (t - Ssz);
            float v;
            if (t >= Ssz && f < Osz) v = ofeed;
            else v = x[((size_t)(row0 + w) * Ssz + ts) * Fsz + f];
            float vs = v * SCL;
            unsigned short u0 = f16_rne(vs);
            float r1 = vs - f16_to_f(u0);
            int slot = ((f >> 3) << 4) | w;
            xfrag[FIDX(0, 0, slot, f & 7)] = u0;
            xfrag[FIDX(0, 1, slot, f & 7)] = f16_rne(r1 * SRES);
        }
        lgkm_barrier();                              // A: fragments complete

        // ---- bh fragments to registers once (9 x ds_read_b128) ----
        short8 bh[NKT];
        #pragma unroll
        for (int kt = 0; kt < NKT; ++kt)
            bh[kt] = *(const short8*)&xfrag[FIDX(kt, 0, l, 0)];

        // ---- pipelined gate GEMM: consume gt g, issue gt g+2; the last two
        //      LOADs target NEXT STEP's gt0/gt1 and fly through the activation
        //      phase (lgkm-only barriers never drain vmcnt) ----
        GEMMGT(A0, A1, 0);  LOADGT(A0, A1, 2);
        GEMMGT(C0, C1, 1);  LOADGT(C0, C1, 3);
        GEMMGT(A0, A1, 2);  LOADGT(A0, A1, 4);
        GEMMGT(C0, C1, 3);  LOADGT(C0, C1, 5);
        GEMMGT(A0, A1, 4);  LOADGT(A0, A1, 6);
        GEMMGT(C0, C1, 5);  LOADGT(C0, C1, 7);
        GEMMGT(A0, A1, 6);  LOADGT(A0, A1, 0);     // next step gt0
        GEMMGT(C0, C1, 7);  LOADGT(C0, C1, 1);     // next step gt1
        lgkm_barrier();                              // B: gates published

        // ---- activations: EXACT f64 path (unchanged numerics) ----
        float gv0[4], gv1[4], gv2[4], gv3[4];
        #pragma unroll
        for (int rr = 0; rr < 4; ++rr) {
            int rowb = (rbase + rr) * GLW;
            gv0[rr] = gate_lds[rowb + 0 * Hsz + j];
            gv1[rr] = gate_lds[rowb + 1 * Hsz + j];
            gv2[rr] = gate_lds[rowb + 2 * Hsz + j];
            gv3[rr] = gate_lds[rowb + 3 * Hsz + j];
        }
        #pragma unroll
        for (int rr = 0; rr < 4; ++rr) {
            double t0 = bias0 + (double)gv0[rr] * INV_SWH;
            double t1 = bias1 + (double)gv1[rr] * INV_SWH;
            double t2 = bias2 + (double)gv2[rr] * INV_SWH;
            double t3 = bias3 + (double)gv3[rr] * INV_SWH;
            double si = sigmoid_d(t0);
            double sf = sigmoid_d(t1);
            double tg = tanh_d(t2);
            double so = sigmoid_d(t3);
            double cn = fma(sf, c_reg[rr], si * tg);
            c_reg[rr] = cn;
            float hf = (float)(so * tanh_d(cn));
            int row = rbase + rr;
            int i32 = j & 31;
            int slot = ((i32 >> 3) << 4) | row;
            float hs = hf * SCL;
            unsigned short u0 = f16_rne(hs);
            float r1 = hs - f16_to_f(u0);
            xfrag[FIDX(ktw, 0, slot, i32 & 7)] = u0;
            xfrag[FIDX(ktw, 1, slot, i32 & 7)] = f16_rne(r1 * SRES);
            if (t >= Ssz - 1) h_f32[row * Hsz + j] = hf;   // exact h for STE readout
        }

        // ---- readout: wave w owns row w (STE f32, dot f64 — unchanged) ----
        if (t >= Ssz - 1) {
            lgkm_barrier();                          // C: h complete
            double a0 = 0.0, a1 = 0.0, a2 = 0.0, a3 = 0.0, a4 = 0.0, a5 = 0.0;
            #pragma unroll
            for (int m = 0; m < 4; ++m) {
                int k = l + 64 * m;
                float hv = h_f32[w * Hsz + k];
                bool b = hv > 0.0f;
                a0 += b ? (double)wfc_lds[0 * Hsz + k] : 0.0;
                a1 += b ? (double)wfc_lds[1 * Hsz + k] : 0.0;
                a2 += b ? (double)wfc_lds[2 * Hsz + k] : 0.0;
                a3 += b ? (double)wfc_lds[3 * Hsz + k] : 0.0;
                a4 += b ? (double)wfc_lds[4 * Hsz + k] : 0.0;
                a5 += b ? (double)wfc_lds[5 * Hsz + k] : 0.0;
            }
            #pragma unroll
            for (int off = 32; off >= 1; off >>= 1) {
                a0 += __shfl_down(a0, off, 64);
                a1 += __shfl_down(a1, off, 64);
                a2 += __shfl_down(a2, off, 64);
                a3 += __shfl_down(a3, off, 64);
                a4 += __shfl_down(a4, off, 64);
                a5 += __shfl_down(a5, off, 64);
            }
            double o0 = (double)b_fc[0] + a0;
            double o1 = (double)b_fc[1] + a1;
            double o2 = (double)b_fc[2] + a2;
            double o3 = (double)b_fc[3] + a3;
            double o4 = (double)b_fc[4] + a4;
            double o5 = (double)b_fc[5] + a5;
            if (l == 0) {
                size_t base = ((size_t)(row0 + w) * (LAsz + 1) + (t - (Ssz - 1))) * Osz;
                out[base + 0] = (float)o0;
                out[base + 1] = (float)o1;
                out[base + 2] = (float)o2;
                out[base + 3] = (float)o3;
                out[base + 4] = (float)o4;
                out[base + 5] = (float)o5;
            }
            // intra-wave o feedback: broadcast lane 0's values, lane f keeps o_f
            double b0 = __shfl(o0, 0, 64);
            double b1 = __shfl(o1, 0, 64);
            double b2 = __shfl(o2, 0, 64);
            double b3 = __shfl(o3, 0, 64);
            double b4 = __shfl(o4, 0, 64);
            double b5 = __shfl(o5, 0, 64);
            ofeed = (float)((l == 0) ? b0 : (l == 1) ? b1 : (l == 2) ? b2 :
                            (l == 3) ? b3 : (l == 4) ? b4 : (l == 5) ? b5 : 0.0);
            // no barrier D needed: feedback is register-resident per wave
        }
        // next iteration's barrier A orders this step's h/x LDS writes vs reads
    }
}

extern "C" void kernel_launch(void* const* d_in, const int* in_sizes, int n_in,
                              void* d_out, int out_size, void* d_ws, size_t ws_size,
                              hipStream_t stream)
{
    const float* x    = (const float*)d_in[0];
    const float* W_ih = (const float*)d_in[1];
    const float* W_hh = (const float*)d_in[2];
    const float* b_ih = (const float*)d_in[3];
    const float* b_hh = (const float*)d_in[4];
    const float* W_fc = (const float*)d_in[5];
    const float* b_fc = (const float*)d_in[6];
    float* out = (float*)d_out;

    unsigned short* wfrag = (unsigned short*)d_ws;   // 64*9*64*32 B = 1.125 MB

    pack_w<<<dim3((NGT * NKT * 64 + 255) / 256), dim3(256), 0, stream>>>(
        W_ih, W_hh, wfrag);

    lstm_persist<<<dim3(Bsz / RT), dim3(NTHR), 0, stream>>>(
        x, wfrag, b_ih, b_hh, W_fc, b_fc, out);
}

// Round 11
// 2391.694 us; speedup vs baseline: 2.5519x; 2.5512x over previous
//
#include <hip/hip_runtime.h>

#define Bsz 2048
#define Ssz 96
#define Fsz 32
#define Hsz 256
#define Osz 6
#define LAsz 32
#define RT 16                 // batch rows per block; grid = 128, full MFMA N-dim
#define NSTEP (Ssz + LAsz)
#define NTHR 1024             // 16 waves; wave w owns batch row w and gate-tiles 4w..4w+3
#define NKT 9                 // K-tiles of 32 over virtual K = 32(x) + 256(h) = 288
#define NGT 64                // gate tiles of 16 (4*256/16)
#define GLW 1044              // f32 row stride of gate_lds
// fp16 2-way split scaling (all exact powers of 2):
#define SCL   1024.0f
#define SRES  2048.0f
#define INV_SR   4.8828125e-4f          // 2^-11
#define INV_SR2  2.384185791015625e-7f  // 2^-22
#define INV_SWH  9.5367431640625e-07    // 2^-20 (applied in f64 combine)

typedef __attribute__((ext_vector_type(8))) short    short8;
typedef __attribute__((ext_vector_type(8))) _Float16 half8;
typedef __attribute__((ext_vector_type(4))) float    f32x4;
typedef __attribute__((ext_vector_type(4))) unsigned int uint4v;

__device__ __forceinline__ half8 as_h8(uint4v v) {
    union { uint4v u; half8 h; } c; c.u = v; return c.h;
}
__device__ __forceinline__ half8 as_h8s(short8 v) {
    union { short8 s; half8 h; } c; c.s = v; return c.h;
}
#define MFMAF16(A, B, C) \
    __builtin_amdgcn_mfma_f32_16x16x32_f16(as_h8(A), as_h8s(B), (C), 0, 0, 0)

__device__ __forceinline__ unsigned short f16_rne(float f) {
    union { _Float16 h; unsigned short u; } c; c.h = (_Float16)f; return c.u;
}
__device__ __forceinline__ float f16_to_f(unsigned short u) {
    union { _Float16 h; unsigned short u; } c; c.u = u; return (float)c.h;
}

// lgkm-only barrier: orders LDS writes/reads across waves WITHOUT draining vmcnt.
// All in-loop cross-wave deps are through LDS (validated in rounds 9/10).
__device__ __forceinline__ void lgkm_barrier() {
    asm volatile("s_waitcnt lgkmcnt(0)" ::: "memory");
    __builtin_amdgcn_s_barrier();
    asm volatile("" ::: "memory");
}

// fragment LDS index: [kt][half][slot][elem] ushorts; slot for (r16,kg) = (kg<<4)|r16
#define FIDX(kt, half, slot, elem) (((((kt) * 2 + (half)) * 64) + (slot)) * 8 + (elem))

// ---------- accurate f64 exp (|rel err| ~1e-14) ----------
__device__ __forceinline__ double exp_d(double x) {
    x = fmin(fmax(x, -700.0), 700.0);
    const double LOG2E = 1.4426950408889634074;
    const double LN2HI = 6.93147180369123816490e-01;
    const double LN2LO = 1.90821492927058770002e-10;
    double n = __builtin_rint(x * LOG2E);
    double r = fma(-n, LN2HI, x);
    r = fma(-n, LN2LO, r);
    double p = 2.5052108385441718775e-08;
    p = fma(p, r, 2.7557319223985890653e-07);
    p = fma(p, r, 2.7557319223985892511e-06);
    p = fma(p, r, 2.4801587301587301566e-05);
    p = fma(p, r, 1.9841269841269841253e-04);
    p = fma(p, r, 1.3888888888888889419e-03);
    p = fma(p, r, 8.3333333333333332177e-03);
    p = fma(p, r, 4.1666666666666664354e-02);
    p = fma(p, r, 1.6666666666666665741e-01);
    p = fma(p, r, 5.0e-01);
    p = fma(p, r, 1.0);
    p = fma(p, r, 1.0);
    long long bits = (long long)(1023 + (int)n) << 52;
    return p * __longlong_as_double(bits);
}
__device__ __forceinline__ double recip_d(double y) {
    double r = (double)(1.0f / (float)y);
    r = fma(fma(-y, r, 1.0), r, r);
    r = fma(fma(-y, r, 1.0), r, r);
    r = fma(fma(-y, r, 1.0), r, r);
    return r;
}
__device__ __forceinline__ double sigmoid_d(double x) { return recip_d(1.0 + exp_d(-x)); }
__device__ __forceinline__ double tanh_d(double x) {
    double ax = fabs(x);
    double t = exp_d(-2.0 * ax);
    double r = (1.0 - t) * recip_d(1.0 + t);
    return x >= 0.0 ? r : -r;
}

// ---------- pre-pass: pack W into scaled fp16 2-way-split MFMA A-fragments ----------
__global__ void pack_w(const float* __restrict__ W_ih,
                       const float* __restrict__ W_hh,
                       unsigned short* __restrict__ wfrag)
{
    int idx = blockIdx.x * 256 + threadIdx.x;
    if (idx >= NGT * NKT * 64) return;
    int L  = idx & 63;
    int tk = idx >> 6;
    int kt = tk % NKT, gt = tk / NKT;
    int gate = gt * 16 + (L & 15);
    int kg   = L >> 4;
    unsigned short* p = wfrag + (size_t)idx * 16;
    #pragma unroll
    for (int i = 0; i < 8; ++i) {
        int vk = kt * 32 + kg * 8 + i;
        float wv = (vk < Fsz) ? W_ih[(size_t)gate * Fsz + vk]
                              : W_hh[(size_t)gate * Hsz + (vk - Fsz)];
        float ws = wv * SCL;
        unsigned short w0 = f16_rne(ws);
        float r1 = ws - f16_to_f(w0);            // exact (Sterbenz)
        p[i]     = w0;
        p[8 + i] = f16_rne(r1 * SRES);
    }
}

__global__ __launch_bounds__(NTHR, 1) void lstm_persist(
    const float* __restrict__ x,
    const unsigned short* __restrict__ wfrag,
    const float* __restrict__ b_ih, const float* __restrict__ b_hh,
    const float* __restrict__ W_fc, const float* __restrict__ b_fc,
    float* __restrict__ out)
{
    __shared__ __align__(16) unsigned short xfrag[NKT * 2 * 64 * 8];  // 18 KB
    __shared__ __align__(16) float gate_lds[RT * GLW];                // 66.8 KB
    __shared__ __align__(16) float h_f32[RT * Hsz];                   // 16 KB
    __shared__ float  wfc_lds[Osz * Hsz];                             // 6 KB

    const int tid   = threadIdx.x;
    const int row0  = blockIdx.x * RT;
    const int w     = tid >> 6;                    // wave id 0..15 (owns batch row w)
    const int l     = tid & 63;
    const int j     = tid & 255;                   // activation channel owned
    const int rg    = tid >> 8;                    // row group 0..3 (wave-uniform)
    const int rbase = rg * 4;                      // activation rows owned
    const int r16   = l & 15;                      // MFMA: batch row (N) — ALL 16 valid
    const int kg    = l >> 4;                      // MFMA: k-group
    const int ktj   = 1 + (j >> 5);                // h-write K-tile for channel j
    const int i32   = j & 31;                      // position of channel j in its tile

    for (int i = tid; i < NKT * 2 * 64 * 8; i += NTHR) xfrag[i] = 0;
    for (int i = tid; i < Osz * Hsz; i += NTHR) wfc_lds[i] = W_fc[i];

    const double bias0 = (double)b_ih[0 * Hsz + j] + (double)b_hh[0 * Hsz + j];
    const double bias1 = (double)b_ih[1 * Hsz + j] + (double)b_hh[1 * Hsz + j];
    const double bias2 = (double)b_ih[2 * Hsz + j] + (double)b_hh[2 * Hsz + j];
    const double bias3 = (double)b_ih[3 * Hsz + j] + (double)b_hh[3 * Hsz + j];

    double c_reg[4];
    #pragma unroll
    for (int r = 0; r < 4; ++r) c_reg[r] = 0.0;

    // wave w owns gate-tiles w*4 .. w*4+3; per-lane record byte base
    const char* wb8 = (const char*)wfrag + ((size_t)(w * 4) * NKT * 64 + l) * 32;

    float ofeed = 0.0f;                            // lanes 0..5: o feedback value

    __syncthreads();

    for (int t = 0; t < NSTEP; ++t) {
        // ---- stage row w's x (or o feedback), scaled fp16 2-split, kt=0 tile ----
        if (l < 32) {
            int f = l;
            int ts = (t < Ssz) ? t : (t - Ssz);
            float v;
            if (t >= Ssz && f < Osz) v = ofeed;
            else v = x[((size_t)(row0 + w) * Ssz + ts) * Fsz + f];
            float vs = v * SCL;
            unsigned short u0 = f16_rne(vs);
            float r1 = vs - f16_to_f(u0);
            int slot = ((f >> 3) << 4) | w;
            xfrag[FIDX(0, 0, slot, f & 7)] = u0;
            xfrag[FIDX(0, 1, slot, f & 7)] = f16_rne(r1 * SRES);
        }
        lgkm_barrier();                              // A: fragments complete

        // ---- bh fragments to registers once (9 x ds_read_b128) ----
        short8 bh[NKT];
        #pragma unroll
        for (int kt = 0; kt < NKT; ++kt)
            bh[kt] = *(const short8*)&xfrag[FIDX(kt, 0, l, 0)];

        // ---- gate GEMM: 4 gate-tiles/wave, inline weight loads (r8 structure) ----
        #pragma unroll 1
        for (int gt = 0; gt < 4; ++gt) {
            const char* wp = wb8 + (size_t)gt * (NKT * 64 * 32);
            f32x4 c0  = {0.f, 0.f, 0.f, 0.f};
            f32x4 c1a = {0.f, 0.f, 0.f, 0.f};
            f32x4 c1b = {0.f, 0.f, 0.f, 0.f};
            f32x4 c2  = {0.f, 0.f, 0.f, 0.f};
            #pragma unroll
            for (int kt = 0; kt < NKT; ++kt) {
                const uint4v* rec = (const uint4v*)(wp + (size_t)kt * 2048);
                uint4v a0 = rec[0];                  // w0 frag
                uint4v a1 = rec[1];                  // w1 frag
                short8 blk = *(const short8*)&xfrag[FIDX(kt, 1, l, 0)];
                c0  = MFMAF16(a0, bh[kt], c0);
                c1a = MFMAF16(a0, blk, c1a);
                c1b = MFMAF16(a1, bh[kt], c1b);
                c2  = MFMAF16(a1, blk, c2);
            }
            f32x4 s;
            s.x = fmaf(c2.x, INV_SR2, fmaf(c1a.x + c1b.x, INV_SR, c0.x));
            s.y = fmaf(c2.y, INV_SR2, fmaf(c1a.y + c1b.y, INV_SR, c0.y));
            s.z = fmaf(c2.z, INV_SR2, fmaf(c1a.z + c1b.z, INV_SR, c0.z));
            s.w = fmaf(c2.w, INV_SR2, fmaf(c1a.w + c1b.w, INV_SR, c0.w));
            // D: col(lane&15)=batch row, row(kg*4+reg)=gate-in-tile — all 16 rows valid
            *(f32x4*)&gate_lds[r16 * GLW + ((w * 4 + gt) << 4) + (kg << 2)] = s;
        }
        lgkm_barrier();                              // B: gates published

        // ---- activations: EXACT f64 path (unchanged numerics) ----
        float gv0[4], gv1[4], gv2[4], gv3[4];
        #pragma unroll
        for (int rr = 0; rr < 4; ++rr) {
            int rowb = (rbase + rr) * GLW;
            gv0[rr] = gate_lds[rowb + 0 * Hsz + j];
            gv1[rr] = gate_lds[rowb + 1 * Hsz + j];
            gv2[rr] = gate_lds[rowb + 2 * Hsz + j];
            gv3[rr] = gate_lds[rowb + 3 * Hsz + j];
        }
        #pragma unroll
        for (int rr = 0; rr < 4; ++rr) {
            double t0 = bias0 + (double)gv0[rr] * INV_SWH;
            double t1 = bias1 + (double)gv1[rr] * INV_SWH;
            double t2 = bias2 + (double)gv2[rr] * INV_SWH;
            double t3 = bias3 + (double)gv3[rr] * INV_SWH;
            double si = sigmoid_d(t0);
            double sf = sigmoid_d(t1);
            double tg = tanh_d(t2);
            double so = sigmoid_d(t3);
            double cn = fma(sf, c_reg[rr], si * tg);
            c_reg[rr] = cn;
            float hf = (float)(so * tanh_d(cn));
            int row = rbase + rr;
            int slot = ((i32 >> 3) << 4) | row;
            float hs = hf * SCL;
            unsigned short u0 = f16_rne(hs);
            float r1 = hs - f16_to_f(u0);
            xfrag[FIDX(ktj, 0, slot, i32 & 7)] = u0;
            xfrag[FIDX(ktj, 1, slot, i32 & 7)] = f16_rne(r1 * SRES);
            if (t >= Ssz - 1) h_f32[row * Hsz + j] = hf;   // exact h for STE readout
        }

        // ---- readout: wave w owns row w (STE f32, dot f64 — unchanged) ----
        if (t >= Ssz - 1) {
            lgkm_barrier();                          // C: h complete
            double a0 = 0.0, a1 = 0.0, a2 = 0.0, a3 = 0.0, a4 = 0.0, a5 = 0.0;
            #pragma unroll
            for (int m = 0; m < 4; ++m) {
                int k = l + 64 * m;
                float hv = h_f32[w * Hsz + k];
                bool b = hv > 0.0f;
                a0 += b ? (double)wfc_lds[0 * Hsz + k] : 0.0;
                a1 += b ? (double)wfc_lds[1 * Hsz + k] : 0.0;
                a2 += b ? (double)wfc_lds[2 * Hsz + k] : 0.0;
                a3 += b ? (double)wfc_lds[3 * Hsz + k] : 0.0;
                a4 += b ? (double)wfc_lds[4 * Hsz + k] : 0.0;
                a5 += b ? (double)wfc_lds[5 * Hsz + k] : 0.0;
            }
            #pragma unroll
            for (int off = 32; off >= 1; off >>= 1) {
                a0 += __shfl_down(a0, off, 64);
                a1 += __shfl_down(a1, off, 64);
                a2 += __shfl_down(a2, off, 64);
                a3 += __shfl_down(a3, off, 64);
                a4 += __shfl_down(a4, off, 64);
                a5 += __shfl_down(a5, off, 64);
            }
            double o0 = (double)b_fc[0] + a0;
            double o1 = (double)b_fc[1] + a1;
            double o2 = (double)b_fc[2] + a2;
            double o3 = (double)b_fc[3] + a3;
            double o4 = (double)b_fc[4] + a4;
            double o5 = (double)b_fc[5] + a5;
            if (l == 0) {
                size_t base = ((size_t)(row0 + w) * (LAsz + 1) + (t - (Ssz - 1))) * Osz;
                out[base + 0] = (float)o0;
                out[base + 1] = (float)o1;
                out[base + 2] = (float)o2;
                out[base + 3] = (float)o3;
                out[base + 4] = (float)o4;
                out[base + 5] = (float)o5;
            }
            // intra-wave o feedback: lane f keeps o_f (register-resident)
            double b0 = __shfl(o0, 0, 64);
            double b1 = __shfl(o1, 0, 64);
            double b2 = __shfl(o2, 0, 64);
            double b3 = __shfl(o3, 0, 64);
            double b4 = __shfl(o4, 0, 64);
            double b5 = __shfl(o5, 0, 64);
            ofeed = (float)((l == 0) ? b0 : (l == 1) ? b1 : (l == 2) ? b2 :
                            (l == 3) ? b3 : (l == 4) ? b4 : (l == 5) ? b5 : 0.0);
        }
        // next iteration's barrier A orders this step's h/x LDS writes vs reads
    }
}

extern "C" void kernel_launch(void* const* d_in, const int* in_sizes, int n_in,
                              void* d_out, int out_size, void* d_ws, size_t ws_size,
                              hipStream_t stream)
{
    const float* x    = (const float*)d_in[0];
    const float* W_ih = (const float*)d_in[1];
    const float* W_hh = (const float*)d_in[2];
    const float* b_ih = (const float*)d_in[3];
    const float* b_hh = (const float*)d_in[4];
    const float* W_fc = (const float*)d_in[5];
    const float* b_fc = (const float*)d_in[6];
    float* out = (float*)d_out;

    unsigned short* wfrag = (unsigned short*)d_ws;   // 64*9*64*32 B = 1.125 MB

    pack_w<<<dim3((NGT * NKT * 64 + 255) / 256), dim3(256), 0, stream>>>(
        W_ih, W_hh, wfrag);

    lstm_persist<<<dim3(Bsz / RT), dim3(NTHR), 0, stream>>>(
        x, wfrag, b_ih, b_hh, W_fc, b_fc, out);
}

// Round 12
// 2198.158 us; speedup vs baseline: 2.7765x; 1.0880x over previous
//
#include <hip/hip_runtime.h>

#define Bsz 2048
#define Ssz 96
#define Fsz 32
#define Hsz 256
#define Osz 6
#define LAsz 32
#define RT 8                  // batch rows per block; grid = 256 = 1 block/CU
#define NSTEP (Ssz + LAsz)
#define NTHR 1024             // 16 waves (4/SIMD); wave w owns gate-tiles 4w..4w+3
#define NKT 9                 // K-tiles of 32 over virtual K = 32(x) + 256(h) = 288
#define NGT 64                // gate tiles of 16 (4*256/16)
#define GLW 1044              // f32 row stride of gate_lds
// fp16 2-way split scaling (all exact powers of 2):
#define SCL   1024.0f
#define SRES  2048.0f
#define INV_SR   4.8828125e-4f          // 2^-11
#define INV_SR2  2.384185791015625e-7f  // 2^-22
#define INV_SWH  9.5367431640625e-07    // 2^-20 (applied in f64 combine)

typedef __attribute__((ext_vector_type(8))) short    short8;
typedef __attribute__((ext_vector_type(8))) _Float16 half8;
typedef __attribute__((ext_vector_type(4))) float    f32x4;
typedef __attribute__((ext_vector_type(4))) unsigned int uint4v;

__device__ __forceinline__ half8 as_h8(uint4v v) {
    union { uint4v u; half8 h; } c; c.u = v; return c.h;
}
__device__ __forceinline__ half8 as_h8s(short8 v) {
    union { short8 s; half8 h; } c; c.s = v; return c.h;
}
#define MFMAF16(A, B, C) \
    __builtin_amdgcn_mfma_f32_16x16x32_f16(as_h8(A), as_h8s(B), (C), 0, 0, 0)

__device__ __forceinline__ unsigned short f16_rne(float f) {
    union { _Float16 h; unsigned short u; } c; c.h = (_Float16)f; return c.u;
}
__device__ __forceinline__ float f16_to_f(unsigned short u) {
    union { _Float16 h; unsigned short u; } c; c.u = u; return (float)c.h;
}

// lgkm-only barrier: orders LDS writes/reads across waves WITHOUT draining vmcnt.
__device__ __forceinline__ void lgkm_barrier() {
    asm volatile("s_waitcnt lgkmcnt(0)" ::: "memory");
    __builtin_amdgcn_s_barrier();
    asm volatile("" ::: "memory");
}

// fragment LDS index: [kt][half][slot][elem] ushorts; slot for (r16,kg) = (kg<<4)|r16
#define FIDX(kt, half, slot, elem) (((((kt) * 2 + (half)) * 64) + (slot)) * 8 + (elem))

// ---------- accurate f64 exp (|rel err| ~1e-14) ----------
__device__ __forceinline__ double exp_d(double x) {
    x = fmin(fmax(x, -700.0), 700.0);
    const double LOG2E = 1.4426950408889634074;
    const double LN2HI = 6.93147180369123816490e-01;
    const double LN2LO = 1.90821492927058770002e-10;
    double n = __builtin_rint(x * LOG2E);
    double r = fma(-n, LN2HI, x);
    r = fma(-n, LN2LO, r);
    double p = 2.5052108385441718775e-08;
    p = fma(p, r, 2.7557319223985890653e-07);
    p = fma(p, r, 2.7557319223985892511e-06);
    p = fma(p, r, 2.4801587301587301566e-05);
    p = fma(p, r, 1.9841269841269841253e-04);
    p = fma(p, r, 1.3888888888888889419e-03);
    p = fma(p, r, 8.3333333333333332177e-03);
    p = fma(p, r, 4.1666666666666664354e-02);
    p = fma(p, r, 1.6666666666666665741e-01);
    p = fma(p, r, 5.0e-01);
    p = fma(p, r, 1.0);
    p = fma(p, r, 1.0);
    long long bits = (long long)(1023 + (int)n) << 52;
    return p * __longlong_as_double(bits);
}
__device__ __forceinline__ double recip_d(double y) {
    double r = (double)(1.0f / (float)y);
    r = fma(fma(-y, r, 1.0), r, r);
    r = fma(fma(-y, r, 1.0), r, r);
    r = fma(fma(-y, r, 1.0), r, r);
    return r;
}
__device__ __forceinline__ double sigmoid_d(double x) { return recip_d(1.0 + exp_d(-x)); }
__device__ __forceinline__ double tanh_d(double x) {
    double ax = fabs(x);
    double t = exp_d(-2.0 * ax);
    double r = (1.0 - t) * recip_d(1.0 + t);
    return x >= 0.0 ? r : -r;
}

// ---------- pre-pass: pack W into scaled fp16 2-way-split MFMA A-fragments ----------
__global__ void pack_w(const float* __restrict__ W_ih,
                       const float* __restrict__ W_hh,
                       unsigned short* __restrict__ wfrag)
{
    int idx = blockIdx.x * 256 + threadIdx.x;
    if (idx >= NGT * NKT * 64) return;
    int L  = idx & 63;
    int tk = idx >> 6;
    int kt = tk % NKT, gt = tk / NKT;
    int gate = gt * 16 + (L & 15);
    int kg   = L >> 4;
    unsigned short* p = wfrag + (size_t)idx * 16;
    #pragma unroll
    for (int i = 0; i < 8; ++i) {
        int vk = kt * 32 + kg * 8 + i;
        float wv = (vk < Fsz) ? W_ih[(size_t)gate * Fsz + vk]
                              : W_hh[(size_t)gate * Hsz + (vk - Fsz)];
        float ws = wv * SCL;
        unsigned short w0 = f16_rne(ws);
        float r1 = ws - f16_to_f(w0);            // exact (Sterbenz)
        p[i]     = w0;
        p[8 + i] = f16_rne(r1 * SRES);
    }
}

__global__ __launch_bounds__(NTHR, 1) void lstm_persist(
    const float* __restrict__ x,
    const unsigned short* __restrict__ wfrag,
    const float* __restrict__ b_ih, const float* __restrict__ b_hh,
    const float* __restrict__ W_fc, const float* __restrict__ b_fc,
    float* __restrict__ out)
{
    __shared__ __align__(16) unsigned short xfrag[NKT * 2 * 64 * 8];  // 18 KB
    __shared__ __align__(16) float gate_lds[RT * GLW];                // 33.4 KB
    __shared__ __align__(16) float h_f32[RT * Hsz];                   // 8 KB
    __shared__ float  wfc_lds[Osz * Hsz];                             // 6 KB

    const int tid   = threadIdx.x;
    const int row0  = blockIdx.x * RT;
    const int w     = tid >> 6;                    // wave id 0..15
    const int l     = tid & 63;
    const int j     = tid & 255;                   // activation channel owned
    const int rg    = tid >> 8;                    // row group 0..3 (wave-uniform)
    const int rbase = rg * 2;                      // 2 activation rows owned
    const int r16   = l & 15;                      // MFMA: batch row (N)
    const int kg    = l >> 4;                      // MFMA: k-group
    const int ktj   = 1 + (j >> 5);                // h-write K-tile for channel j
    const int i32   = j & 31;                      // position of channel j in its tile

    for (int i = tid; i < NKT * 2 * 64 * 8; i += NTHR) xfrag[i] = 0;
    for (int i = tid; i < Osz * Hsz; i += NTHR) wfc_lds[i] = W_fc[i];

    const double bias0 = (double)b_ih[0 * Hsz + j] + (double)b_hh[0 * Hsz + j];
    const double bias1 = (double)b_ih[1 * Hsz + j] + (double)b_hh[1 * Hsz + j];
    const double bias2 = (double)b_ih[2 * Hsz + j] + (double)b_hh[2 * Hsz + j];
    const double bias3 = (double)b_ih[3 * Hsz + j] + (double)b_hh[3 * Hsz + j];

    double c_reg[2];
    c_reg[0] = 0.0; c_reg[1] = 0.0;

    // wave w owns gate-tiles w*4 .. w*4+3; per-lane record byte base
    const char* wb8 = (const char*)wfrag + ((size_t)(w * 4) * NKT * 64 + l) * 32;

    float ofeed = 0.0f;                            // waves 0-7, lanes 0..5

    __syncthreads();

    for (int t = 0; t < NSTEP; ++t) {
        // ---- stage row w's x (or o feedback), scaled fp16 2-split, kt=0 tile ----
        if (w < RT && l < 32) {
            int f = l;
            int ts = (t < Ssz) ? t : (t - Ssz);
            float v;
            if (t >= Ssz && f < Osz) v = ofeed;
            else v = x[((size_t)(row0 + w) * Ssz + ts) * Fsz + f];
            float vs = v * SCL;
            unsigned short u0 = f16_rne(vs);
            float r1 = vs - f16_to_f(u0);
            int slot = ((f >> 3) << 4) | w;
            xfrag[FIDX(0, 0, slot, f & 7)] = u0;
            xfrag[FIDX(0, 1, slot, f & 7)] = f16_rne(r1 * SRES);
        }
        lgkm_barrier();                              // A: fragments complete

        // ---- bh fragments to registers once (9 x ds_read_b128) ----
        short8 bh[NKT];
        #pragma unroll
        for (int kt = 0; kt < NKT; ++kt)
            bh[kt] = *(const short8*)&xfrag[FIDX(kt, 0, l, 0)];

        // ---- gate GEMM: 4 gate-tiles/wave, inline weight loads (r8 structure) ----
        #pragma unroll 1
        for (int gt = 0; gt < 4; ++gt) {
            const char* wp = wb8 + (size_t)gt * (NKT * 64 * 32);
            f32x4 c0  = {0.f, 0.f, 0.f, 0.f};
            f32x4 c1a = {0.f, 0.f, 0.f, 0.f};
            f32x4 c1b = {0.f, 0.f, 0.f, 0.f};
            f32x4 c2  = {0.f, 0.f, 0.f, 0.f};
            #pragma unroll
            for (int kt = 0; kt < NKT; ++kt) {
                const uint4v* rec = (const uint4v*)(wp + (size_t)kt * 2048);
                uint4v a0 = rec[0];                  // w0 frag
                uint4v a1 = rec[1];                  // w1 frag
                short8 blk = *(const short8*)&xfrag[FIDX(kt, 1, l, 0)];
                c0  = MFMAF16(a0, bh[kt], c0);
                c1a = MFMAF16(a0, blk, c1a);
                c1b = MFMAF16(a1, bh[kt], c1b);
                c2  = MFMAF16(a1, blk, c2);
            }
            if (r16 < RT) {
                f32x4 s;
                s.x = fmaf(c2.x, INV_SR2, fmaf(c1a.x + c1b.x, INV_SR, c0.x));
                s.y = fmaf(c2.y, INV_SR2, fmaf(c1a.y + c1b.y, INV_SR, c0.y));
                s.z = fmaf(c2.z, INV_SR2, fmaf(c1a.z + c1b.z, INV_SR, c0.z));
                s.w = fmaf(c2.w, INV_SR2, fmaf(c1a.w + c1b.w, INV_SR, c0.w));
                // D: col(lane&15)=batch row, row(kg*4+reg)=gate-in-tile
                *(f32x4*)&gate_lds[r16 * GLW + ((w * 4 + gt) << 4) + (kg << 2)] = s;
            }
        }
        lgkm_barrier();                              // B: gates published

        // ---- activations: EXACT f64 path, 2 cells/thread ----
        float gv0[2], gv1[2], gv2[2], gv3[2];
        #pragma unroll
        for (int rr = 0; rr < 2; ++rr) {
            int rowb = (rbase + rr) * GLW;
            gv0[rr] = gate_lds[rowb + 0 * Hsz + j];
            gv1[rr] = gate_lds[rowb + 1 * Hsz + j];
            gv2[rr] = gate_lds[rowb + 2 * Hsz + j];
            gv3[rr] = gate_lds[rowb + 3 * Hsz + j];
        }
        #pragma unroll
        for (int rr = 0; rr < 2; ++rr) {
            double t0 = bias0 + (double)gv0[rr] * INV_SWH;
            double t1 = bias1 + (double)gv1[rr] * INV_SWH;
            double t2 = bias2 + (double)gv2[rr] * INV_SWH;
            double t3 = bias3 + (double)gv3[rr] * INV_SWH;
            double si = sigmoid_d(t0);
            double sf = sigmoid_d(t1);
            double tg = tanh_d(t2);
            double so = sigmoid_d(t3);
            double cn = fma(sf, c_reg[rr], si * tg);
            c_reg[rr] = cn;
            float hf = (float)(so * tanh_d(cn));
            int row = rbase + rr;
            int slot = ((i32 >> 3) << 4) | row;
            float hs = hf * SCL;
            unsigned short u0 = f16_rne(hs);
            float r1 = hs - f16_to_f(u0);
            xfrag[FIDX(ktj, 0, slot, i32 & 7)] = u0;
            xfrag[FIDX(ktj, 1, slot, i32 & 7)] = f16_rne(r1 * SRES);
            if (t >= Ssz - 1) h_f32[row * Hsz + j] = hf;   // exact h for STE readout
        }

        // ---- readout: waves 0-7 own rows 0-7 (STE f32, dot f64 — unchanged) ----
        if (t >= Ssz - 1) {
            lgkm_barrier();                          // C: h complete (all waves)
            if (w < RT) {
                double a0 = 0.0, a1 = 0.0, a2 = 0.0, a3 = 0.0, a4 = 0.0, a5 = 0.0;
                #pragma unroll
                for (int m = 0; m < 4; ++m) {
                    int k = l + 64 * m;
                    float hv = h_f32[w * Hsz + k];
                    bool b = hv > 0.0f;
                    a0 += b ? (double)wfc_lds[0 * Hsz + k] : 0.0;
                    a1 += b ? (double)wfc_lds[1 * Hsz + k] : 0.0;
                    a2 += b ? (double)wfc_lds[2 * Hsz + k] : 0.0;
                    a3 += b ? (double)wfc_lds[3 * Hsz + k] : 0.0;
                    a4 += b ? (double)wfc_lds[4 * Hsz + k] : 0.0;
                    a5 += b ? (double)wfc_lds[5 * Hsz + k] : 0.0;
                }
                #pragma unroll
                for (int off = 32; off >= 1; off >>= 1) {
                    a0 += __shfl_down(a0, off, 64);
                    a1 += __shfl_down(a1, off, 64);
                    a2 += __shfl_down(a2, off, 64);
                    a3 += __shfl_down(a3, off, 64);
                    a4 += __shfl_down(a4, off, 64);
                    a5 += __shfl_down(a5, off, 64);
                }
                double o0 = (double)b_fc[0] + a0;
                double o1 = (double)b_fc[1] + a1;
                double o2 = (double)b_fc[2] + a2;
                double o3 = (double)b_fc[3] + a3;
                double o4 = (double)b_fc[4] + a4;
                double o5 = (double)b_fc[5] + a5;
                if (l == 0) {
                    size_t base = ((size_t)(row0 + w) * (LAsz + 1) + (t - (Ssz - 1))) * Osz;
                    out[base + 0] = (float)o0;
                    out[base + 1] = (float)o1;
                    out[base + 2] = (float)o2;
                    out[base + 3] = (float)o3;
                    out[base + 4] = (float)o4;
                    out[base + 5] = (float)o5;
                }
                // intra-wave o feedback: lane f keeps o_f (register-resident)
                double b0 = __shfl(o0, 0, 64);
                double b1 = __shfl(o1, 0, 64);
                double b2 = __shfl(o2, 0, 64);
                double b3 = __shfl(o3, 0, 64);
                double b4 = __shfl(o4, 0, 64);
                double b5 = __shfl(o5, 0, 64);
                ofeed = (float)((l == 0) ? b0 : (l == 1) ? b1 : (l == 2) ? b2 :
                                (l == 3) ? b3 : (l == 4) ? b4 : (l == 5) ? b5 : 0.0);
            }
        }
        // next iteration's barrier A orders this step's h/x LDS writes vs reads
    }
}

extern "C" void kernel_launch(void* const* d_in, const int* in_sizes, int n_in,
                              void* d_out, int out_size, void* d_ws, size_t ws_size,
                              hipStream_t stream)
{
    const float* x    = (const float*)d_in[0];
    const float* W_ih = (const float*)d_in[1];
    const float* W_hh = (const float*)d_in[2];
    const float* b_ih = (const float*)d_in[3];
    const float* b_hh = (const float*)d_in[4];
    const float* W_fc = (const float*)d_in[5];
    const float* b_fc = (const float*)d_in[6];
    float* out = (float*)d_out;

    unsigned short* wfrag = (unsigned short*)d_ws;   // 64*9*64*32 B = 1.125 MB

    pack_w<<<dim3((NGT * NKT * 64 + 255) / 256), dim3(256), 0, stream>>>(
        W_ih, W_hh, wfrag);

    lstm_persist<<<dim3(Bsz / RT), dim3(NTHR), 0, stream>>>(
        x, wfrag, b_ih, b_hh, W_fc, b_fc, out);
}